// Round 4
// baseline (11727.219 us; speedup 1.0000x reference)
//
#include <hip/hip_runtime.h>
#include <hip/hip_bf16.h>

#define Bsz 4096
#define Dsz 256
#define Hsz 512
#define Tsz 45

typedef __attribute__((ext_vector_type(8))) short short8;
typedef __attribute__((ext_vector_type(4))) float f32x4;
typedef __attribute__((ext_vector_type(4))) unsigned short us4;
using bf16 = __hip_bfloat16;

__device__ __forceinline__ float sigf(float x)   { return 1.0f / (1.0f + __expf(-x)); }
__device__ __forceinline__ float tanhft(float x) { return 1.0f - 2.0f / (__expf(2.0f * x) + 1.0f); }
__device__ __forceinline__ float b2f(unsigned short u) { return __uint_as_float((unsigned)u << 16); }

__device__ __forceinline__ void gload16(const void* g, void* l) {
    __builtin_amdgcn_global_load_lds((const __attribute__((address_space(1))) void*)g,
                                     (__attribute__((address_space(3))) void*)l, 16, 0, 0);
}

// ---------------------------------------------------------------------------
// Weight convert / transpose (one-shot).
// ---------------------------------------------------------------------------
__global__ void k_conv(const float* __restrict__ ef,   const float* __restrict__ ctx,
                       const float* __restrict__ Whi,  const float* __restrict__ Wci,
                       const float* __restrict__ Wih0, const float* __restrict__ Whh0,
                       const float* __restrict__ Wih1, const float* __restrict__ Whh1,
                       const float* __restrict__ Wo1,  const float* __restrict__ Wg1,
                       bf16* __restrict__ efb,  bf16* __restrict__ ctxb,
                       bf16* __restrict__ Wit,  bf16* __restrict__ Wt0,
                       bf16* __restrict__ Wt1,  bf16* __restrict__ Wo1t,
                       bf16* __restrict__ Wg1t)
{
    size_t tid = (size_t)blockIdx.x * blockDim.x + threadIdx.x;
    size_t gsz = (size_t)gridDim.x * blockDim.x;
    for (size_t i = tid; i < (size_t)Bsz * Dsz; i += gsz) {
        efb[i]  = __float2bfloat16(ef[i]);
        ctxb[i] = __float2bfloat16(ctx[i]);
    }
    for (size_t i = tid; i < 2048ull * 512; i += gsz) {     // Wt0[n][k] = W_hh0[k][n]
        size_t n = i >> 9, k = i & 511;
        Wt0[i] = __float2bfloat16(Whh0[k * 2048 + n]);
    }
    for (size_t i = tid; i < 2048ull * 1024; i += gsz) {    // Wt1[n][k] = [W_ih1; W_hh1][k][n]
        size_t n = i >> 10, k = i & 1023;
        Wt1[i] = __float2bfloat16(k < 512 ? Wih1[k * 2048 + n] : Whh1[(k - 512) * 2048 + n]);
    }
    for (size_t i = tid; i < 32ull * 512; i += gsz) {       // Wo1t/Wg1t[c][k]
        size_t c = i >> 9, k = i & 511;
        Wo1t[i] = __float2bfloat16(Wo1[k * 32 + c]);
        Wg1t[i] = __float2bfloat16(Wg1[k * 32 + c]);
    }
    for (size_t i = tid; i < 4096ull * 256; i += gsz) {     // Wit[n][k]: [Wh_init;Wc_init;W_ih0[1:]]^T
        size_t n = i >> 8, k = i & 255;
        float v = (n < 1024) ? Whi[k * 1024 + n]
                : (n < 2048) ? Wci[k * 1024 + (n - 1024)]
                             : Wih0[(1 + k) * 2048 + (n - 2048)];
        Wit[i] = __float2bfloat16(v);
    }
}

// ---------------------------------------------------------------------------
// Init GEMM: [h_init | c_init | ctx_gates]. ctx_gates stored [b][j][4 gates].
// ---------------------------------------------------------------------------
__global__ void __launch_bounds__(256)
k_init(const bf16* __restrict__ efb, const bf16* __restrict__ ctxb,
       const bf16* __restrict__ Wit,
       const float* __restrict__ bh,  const float* __restrict__ bc,
       const float* __restrict__ bi0, const float* __restrict__ bh0,
       bf16* __restrict__ h0, bf16* __restrict__ h1,
       float* __restrict__ c0, float* __restrict__ c1,
       bf16* __restrict__ ctxg)
{
    const int t = threadIdx.x, lane = t & 63, w = t >> 6;
    const int wr = w >> 1, wc = w & 1;
    const int lq = lane >> 4, ln = lane & 15;
    const int m0 = blockIdx.x * 128, n0 = blockIdx.y * 64;
    const bf16* A = (n0 < 2048) ? efb : ctxb;

    f32x4 zero = {0.f, 0.f, 0.f, 0.f};
    f32x4 acc[4][2];
#pragma unroll
    for (int r = 0; r < 4; ++r)
#pragma unroll
        for (int c = 0; c < 2; ++c) acc[r][c] = zero;

    for (int k0 = 0; k0 < 256; k0 += 32) {
        short8 af[4];
#pragma unroll
        for (int r = 0; r < 4; ++r)
            af[r] = *(const short8*)(A + (size_t)(m0 + wr * 64 + r * 16 + ln) * 256 + k0 + lq * 8);
#pragma unroll
        for (int c = 0; c < 2; ++c) {
            short8 bv = *(const short8*)(Wit + (size_t)(n0 + wc * 32 + c * 16 + ln) * 256 + k0 + lq * 8);
#pragma unroll
            for (int r = 0; r < 4; ++r)
                acc[r][c] = __builtin_amdgcn_mfma_f32_16x16x32_bf16(af[r], bv, acc[r][c], 0, 0, 0);
        }
    }
#pragma unroll
    for (int r = 0; r < 4; ++r)
#pragma unroll
        for (int c = 0; c < 2; ++c)
#pragma unroll
            for (int e = 0; e < 4; ++e) {
                int b = m0 + wr * 64 + r * 16 + lq * 4 + e;
                int n = n0 + wc * 32 + c * 16 + ln;
                float v = acc[r][c][e];
                if (n < 1024) {
                    v += bh[n];
                    if (n < 512) h0[(size_t)b * 512 + n]       = __float2bfloat16(v);
                    else         h1[(size_t)b * 512 + n - 512] = __float2bfloat16(v);
                } else if (n < 2048) {
                    int m = n - 1024; v += bc[m];
                    if (m < 512) c0[(size_t)b * 512 + m]       = v;
                    else         c1[(size_t)b * 512 + m - 512] = v;
                } else {
                    int j = n - 2048;
                    ctxg[(size_t)b * 2048 + (j & 511) * 4 + (j >> 9)] =
                        __float2bfloat16(v + bi0[j] + bh0[j]);
                }
            }
}

// ---------------------------------------------------------------------------
// intent head for 128 rows at m0 (all 4 waves; wave w: rows w*32..+32).
// ---------------------------------------------------------------------------
__device__ __forceinline__ void intent_head(
    const bf16* __restrict__ h, const bf16* __restrict__ W1t,
    const float* __restrict__ b1, const float* __restrict__ W2, float b2s,
    int m0, float* sitp, float* outp, int ostride)
{
    const int t = threadIdx.x, lane = t & 63, w = t >> 6;
    const int lq = lane >> 4, ln = lane & 15;
    f32x4 zero = {0.f, 0.f, 0.f, 0.f};
    f32x4 acc[2][2];
#pragma unroll
    for (int r = 0; r < 2; ++r)
#pragma unroll
        for (int c = 0; c < 2; ++c) acc[r][c] = zero;

#pragma unroll
    for (int k0 = 0; k0 < 512; k0 += 32) {
        short8 av[2], bv[2];
#pragma unroll
        for (int r = 0; r < 2; ++r)
            av[r] = *(const short8*)(h + (size_t)(m0 + w * 32 + r * 16 + ln) * 512 + k0 + lq * 8);
#pragma unroll
        for (int c = 0; c < 2; ++c)
            bv[c] = *(const short8*)(W1t + (size_t)(c * 16 + ln) * 512 + k0 + lq * 8);
#pragma unroll
        for (int r = 0; r < 2; ++r)
#pragma unroll
            for (int c = 0; c < 2; ++c)
                acc[r][c] = __builtin_amdgcn_mfma_f32_16x16x32_bf16(av[r], bv[c], acc[r][c], 0, 0, 0);
    }
#pragma unroll
    for (int r = 0; r < 2; ++r)
#pragma unroll
        for (int e = 0; e < 4; ++e) {
            float v = 0.f;
#pragma unroll
            for (int c = 0; c < 2; ++c) {
                int col = c * 16 + ln;
                v += fmaxf(acc[r][c][e] + b1[col], 0.f) * W2[col];
            }
            v += __shfl_xor(v, 1);
            v += __shfl_xor(v, 2);
            v += __shfl_xor(v, 4);
            v += __shfl_xor(v, 8);
            int row = w * 32 + r * 16 + lq * 4 + e;
            if (ln == 0) {
                float p = sigf(v + b2s);
                if (sitp) sitp[row] = p;
                if (outp) outp[(size_t)(m0 + row) * ostride] = p;
            }
        }
}

// ---------------------------------------------------------------------------
// Staging: tile (128 rows x 64 K) of A and (4g x 32 n x 64 K) of B into LDS,
// 8-slot XOR swizzle (slot = chunk ^ (row&7)) pre-applied on the GLOBAL side.
// ---------------------------------------------------------------------------
template <int L0>
__device__ __forceinline__ void stage(const bf16* __restrict__ hA, const bf16* __restrict__ hB,
                                      const bf16* __restrict__ Wt,
                                      int m0, int j0, int k0, bf16* Ab, bf16* Bb, int t)
{
    constexpr int KW = L0 ? 512 : 1024;
#pragma unroll
    for (int i = 0; i < 4; ++i) {
        int f = i * 256 + t;
        int row = f >> 3, slot = f & 7;
        int kk = k0 + ((slot ^ (row & 7)) << 3);
        const bf16* src;
        if (L0) src = hA + (size_t)(m0 + row) * Hsz + kk;
        else    src = (kk < 512) ? hA + (size_t)(m0 + row) * Hsz + kk
                                 : hB + (size_t)(m0 + row) * Hsz + (kk - 512);
        gload16(src, (char*)Ab + (size_t)f * 16);
    }
#pragma unroll
    for (int i = 0; i < 4; ++i) {
        int f = i * 256 + t;
        int brow = f >> 3, slot = f & 7;
        int g = brow >> 5, n = brow & 31;
        int kc = slot ^ (brow & 7);
        gload16(Wt + (size_t)(g * 512 + j0 + n) * KW + k0 + kc * 8, (char*)Bb + (size_t)f * 16);
    }
}

// one 64-K LDS tile of MFMA work (4 gates x 4 row-frags x 2 k-halves)
__device__ __forceinline__ void mfma_tile(const bf16* Ab, const bf16* Bb,
                                          int wr, int wc, int lq, int ln,
                                          f32x4 (&acc)[4][4])
{
#pragma unroll
    for (int kk2 = 0; kk2 < 2; ++kk2) {
        short8 af[4], bfr[4];
#pragma unroll
        for (int r = 0; r < 4; ++r) {
            int row = wr * 64 + r * 16 + ln;
            int slot = (kk2 * 4 + lq) ^ (row & 7);
            af[r] = *(const short8*)(Ab + ((size_t)row * 8 + slot) * 8);
        }
#pragma unroll
        for (int g = 0; g < 4; ++g) {
            int brow = g * 32 + wc * 16 + ln;
            int slot = (kk2 * 4 + lq) ^ (brow & 7);
            bfr[g] = *(const short8*)(Bb + ((size_t)brow * 8 + slot) * 8);
        }
#pragma unroll
        for (int g = 0; g < 4; ++g)
#pragma unroll
            for (int r = 0; r < 4; ++r)
                acc[g][r] = __builtin_amdgcn_mfma_f32_16x16x32_bf16(af[r], bfr[g], acc[g][r], 0, 0, 0);
    }
}

// LSTM cell epilogue. C/D frag: col=lane&15, row=(lane>>4)*4+reg
template <int L0>
__device__ __forceinline__ void cell_epi(f32x4 (&acc)[4][4], const float* sreg,
                                         const bf16* __restrict__ ctxg,
                                         const float* __restrict__ w0row,
                                         const float* __restrict__ b1, const float* __restrict__ b2,
                                         float* __restrict__ cbuf, bf16* __restrict__ hout,
                                         int m0, int j0, int wr, int wc, int lq, int ln)
{
    const int jl = j0 + wc * 16 + ln;
    float addc[4];
#pragma unroll
    for (int g = 0; g < 4; ++g)
        addc[g] = L0 ? w0row[g * 512 + jl] : (b1[g * 512 + jl] + b2[g * 512 + jl]);

#pragma unroll
    for (int r = 0; r < 4; ++r)
#pragma unroll
        for (int e = 0; e < 4; ++e) {
            int b = m0 + wr * 64 + r * 16 + lq * 4 + e;
            float pre[4];
#pragma unroll
            for (int g = 0; g < 4; ++g) pre[g] = acc[g][r][e];
            if (L0) {
                float it = sreg[r * 4 + e];
                us4 cg = *(const us4*)((const unsigned short*)ctxg + (size_t)b * 2048 + jl * 4);
#pragma unroll
                for (int g = 0; g < 4; ++g) pre[g] += b2f(cg[g]) + it * addc[g];
            } else {
#pragma unroll
                for (int g = 0; g < 4; ++g) pre[g] += addc[g];
            }
            float ig = sigf(pre[0]), fg = sigf(pre[1]);
            float gg = tanhft(pre[2]), og = sigf(pre[3]);
            size_t idx = (size_t)b * Hsz + jl;
            float cn = fg * cbuf[idx] + ig * gg;
            cbuf[idx] = cn;
            hout[idx] = __float2bfloat16(og * tanhft(cn));
        }
}

// 16-WG row-band group barrier (device-scope; group is XCD-local by mapping)
__device__ __forceinline__ void group_barrier(unsigned* cnt, unsigned target) {
    __syncthreads();
    __threadfence();                                   // release
    if (threadIdx.x == 0) {
        __hip_atomic_fetch_add(cnt, 1u, __ATOMIC_RELAXED, __HIP_MEMORY_SCOPE_AGENT);
        while (__hip_atomic_load(cnt, __ATOMIC_RELAXED, __HIP_MEMORY_SCOPE_AGENT) < target)
            __builtin_amdgcn_s_sleep(1);
    }
    __syncthreads();
    __threadfence();                                   // acquire
}

// ---------------------------------------------------------------------------
// Persistent kernel: all 45 steps. 512 WGs = 32 row-band groups x 16 jblks,
// mapped so each group's 16 WGs share one XCD (bid&7 = XCD round-robin).
// Groups are fully independent (row-disjoint state); 2 group-barriers/step.
// ---------------------------------------------------------------------------
struct KP {
    const bf16 *Wt0, *Wt1, *Wo1t, *Wg1t, *ctxg;
    const float *w0row, *bi1, *bh1, *bo1, *Wo2, *bo2, *bg1, *Wg2, *bg2, *ii;
    bf16 *h0x, *h0y, *h1x, *h1y;
    float *c0, *c1, *out;
    unsigned* bar;
};

__global__ void __launch_bounds__(256, 2) k_loop(KP p)
{
    __shared__ __align__(16) char lds[65536];
    __shared__ float sitp[128];
    bf16* A0 = (bf16*)lds;
    bf16* A1 = (bf16*)(lds + 16384);
    bf16* B0 = (bf16*)(lds + 32768);
    bf16* B1 = (bf16*)(lds + 49152);

    const int t = threadIdx.x, lane = t & 63, w = t >> 6;
    const int wr = w >> 1, wc = w & 1, lq = lane >> 4, ln = lane & 15;
    const int bid = blockIdx.x;
    const int mblk = (bid & 7) * 4 + ((bid >> 3) & 3);   // group: 16 WGs, one XCD
    const int jblk = bid >> 5;
    const int m0 = mblk * 128, j0 = jblk * 32;
    unsigned* grp = p.bar + mblk;
    unsigned gen = 0;

    f32x4 zero = {0.f, 0.f, 0.f, 0.f};

    for (int s = 0; s < Tsz; ++s) {
        const bf16* h0in  = (s & 1) ? p.h0y : p.h0x;
        bf16*       h0out = (s & 1) ? p.h0x : p.h0y;
        const bf16* h1in  = (s & 1) ? p.h1y : p.h1x;
        bf16*       h1out = (s & 1) ? p.h1x : p.h1y;

        // ---------------- phase A: layer-0 gates + cell (+ intent head) ----
        stage<1>(h0in, nullptr, p.Wt0, m0, j0, 0, A0, B0, t);
        if (s == 0) {
            if (t < 128) sitp[t] = p.ii[m0 + t];
        } else {
            intent_head(h1in, p.Wo1t, p.bo1, p.Wo2, p.bo2[0], m0, sitp,
                        (jblk == 0) ? p.out + (s - 1) : nullptr, Tsz);
        }
        __syncthreads();                          // sit visible + tile0 landed
        float sreg[16];
#pragma unroll
        for (int r = 0; r < 4; ++r)
#pragma unroll
            for (int e = 0; e < 4; ++e)
                sreg[r * 4 + e] = sitp[wr * 64 + r * 16 + lq * 4 + e];

        {
            f32x4 acc[4][4];
#pragma unroll
            for (int g = 0; g < 4; ++g)
#pragma unroll
                for (int r = 0; r < 4; ++r) acc[g][r] = zero;
#pragma unroll 2
            for (int kt = 0; kt < 8; ++kt) {
                if (kt + 1 < 8)
                    stage<1>(h0in, nullptr, p.Wt0, m0, j0, (kt + 1) * 64,
                             (kt & 1) ? A0 : A1, (kt & 1) ? B0 : B1, t);
                mfma_tile((kt & 1) ? A1 : A0, (kt & 1) ? B1 : B0, wr, wc, lq, ln, acc);
                if (kt + 1 < 8) __syncthreads();
            }
            cell_epi<1>(acc, sreg, p.ctxg, p.w0row, nullptr, nullptr,
                        p.c0, h0out, m0, j0, wr, wc, lq, ln);
        }
        ++gen; group_barrier(grp, gen * 16);

        // ---------------- phase B: layer-1 gates + cell --------------------
        stage<0>(h0out, h1in, p.Wt1, m0, j0, 0, A0, B0, t);
        __syncthreads();
        {
            f32x4 acc[4][4];
#pragma unroll
            for (int g = 0; g < 4; ++g)
#pragma unroll
                for (int r = 0; r < 4; ++r) acc[g][r] = zero;
#pragma unroll 2
            for (int kt = 0; kt < 16; ++kt) {
                if (kt + 1 < 16)
                    stage<0>(h0out, h1in, p.Wt1, m0, j0, (kt + 1) * 64,
                             (kt & 1) ? A0 : A1, (kt & 1) ? B0 : B1, t);
                mfma_tile((kt & 1) ? A1 : A0, (kt & 1) ? B1 : B0, wr, wc, lq, ln, acc);
                if (kt + 1 < 16) __syncthreads();
            }
            cell_epi<0>(acc, nullptr, nullptr, nullptr, p.bi1, p.bh1,
                        p.c1, h1out, m0, j0, wr, wc, lq, ln);
        }
        ++gen; group_barrier(grp, gen * 16);
    }

    // final heads: s=44 (even) wrote h1y; group barrier above covers it
    if (jblk == 0)
        intent_head(p.h1y, p.Wo1t, p.bo1, p.Wo2, p.bo2[0], m0, nullptr,
                    p.out + 44, Tsz);
    if (jblk == 1)
        intent_head(p.h1y, p.Wg1t, p.bg1, p.Wg2, p.bg2[0], m0, nullptr,
                    p.out + (size_t)Bsz * Tsz, 1);
}

// ---------------------------------------------------------------------------
extern "C" void kernel_launch(void* const* d_in, const int* in_sizes, int n_in,
                              void* d_out, int out_size, void* d_ws, size_t ws_size,
                              hipStream_t stream)
{
    const float* ef   = (const float*)d_in[0];
    const float* ctx  = (const float*)d_in[1];
    const float* ii   = (const float*)d_in[2];
    const float* Whi  = (const float*)d_in[3];
    const float* bh   = (const float*)d_in[4];
    const float* Wci  = (const float*)d_in[5];
    const float* bc   = (const float*)d_in[6];
    const float* Wih0 = (const float*)d_in[7];
    const float* Whh0 = (const float*)d_in[8];
    const float* bi0  = (const float*)d_in[9];
    const float* bh0  = (const float*)d_in[10];
    const float* Wih1 = (const float*)d_in[11];
    const float* Whh1 = (const float*)d_in[12];
    const float* bi1  = (const float*)d_in[13];
    const float* bh1  = (const float*)d_in[14];
    const float* Wo1  = (const float*)d_in[15];
    const float* bo1  = (const float*)d_in[16];
    const float* Wo2  = (const float*)d_in[17];
    const float* bo2  = (const float*)d_in[18];
    const float* Wg1  = (const float*)d_in[19];
    const float* bg1  = (const float*)d_in[20];
    const float* Wg2  = (const float*)d_in[21];
    const float* bg2  = (const float*)d_in[22];
    float* out = (float*)d_out;

    char* ws = (char*)d_ws;
    size_t off = 0;
    auto take = [&](size_t bytes) -> char* {
        char* pp = ws + off;
        off += (bytes + 255) & ~(size_t)255;
        return pp;
    };
    bf16* Wt0    = (bf16*)take(2048ull * 512 * 2);
    bf16* Wt1    = (bf16*)take(2048ull * 1024 * 2);
    bf16* Wo1t   = (bf16*)take(32ull * 512 * 2);
    bf16* Wg1t   = (bf16*)take(32ull * 512 * 2);
    bf16* Wit    = (bf16*)take(4096ull * 256 * 2);
    bf16* efb    = (bf16*)take((size_t)Bsz * Dsz * 2);
    bf16* ctxb   = (bf16*)take((size_t)Bsz * Dsz * 2);
    bf16* h0x    = (bf16*)take((size_t)Bsz * Hsz * 2);
    bf16* h0y    = (bf16*)take((size_t)Bsz * Hsz * 2);
    bf16* h1x    = (bf16*)take((size_t)Bsz * Hsz * 2);
    bf16* h1y    = (bf16*)take((size_t)Bsz * Hsz * 2);
    float* c0    = (float*)take((size_t)Bsz * Hsz * 4);
    float* c1    = (float*)take((size_t)Bsz * Hsz * 4);
    bf16* ctxg   = (bf16*)take((size_t)Bsz * 2048 * 2);
    unsigned* bar = (unsigned*)take(32 * sizeof(unsigned));
    (void)ws_size; (void)in_sizes; (void)n_in; (void)out_size;

    hipMemsetAsync(bar, 0, 32 * sizeof(unsigned), stream);
    k_conv<<<2048, 256, 0, stream>>>(ef, ctx, Whi, Wci, Wih0, Whh0, Wih1, Whh1, Wo1, Wg1,
                                     efb, ctxb, Wit, Wt0, Wt1, Wo1t, Wg1t);
    k_init<<<dim3(32, 64), 256, 0, stream>>>(efb, ctxb, Wit, bh, bc, bi0, bh0,
                                             h0x, h1x, c0, c1, ctxg);

    KP p;
    p.Wt0 = Wt0; p.Wt1 = Wt1; p.Wo1t = Wo1t; p.Wg1t = Wg1t; p.ctxg = ctxg;
    p.w0row = Wih0; p.bi1 = bi1; p.bh1 = bh1;
    p.bo1 = bo1; p.Wo2 = Wo2; p.bo2 = bo2;
    p.bg1 = bg1; p.Wg2 = Wg2; p.bg2 = bg2; p.ii = ii;
    p.h0x = h0x; p.h0y = h0y; p.h1x = h1x; p.h1y = h1y;
    p.c0 = c0; p.c1 = c1; p.out = out; p.bar = bar;

    k_loop<<<512, 256, 0, stream>>>(p);
}

// Round 5
// 3428.016 us; speedup vs baseline: 3.4210x; 3.4210x over previous
//
#include <hip/hip_runtime.h>
#include <hip/hip_bf16.h>

#define Bsz 4096
#define Dsz 256
#define Hsz 512
#define Tsz 45

typedef __attribute__((ext_vector_type(8))) short short8;
typedef __attribute__((ext_vector_type(4))) float f32x4;
typedef __attribute__((ext_vector_type(4))) unsigned short us4;
using bf16 = __hip_bfloat16;

__device__ __forceinline__ float sigf(float x)   { return 1.0f / (1.0f + __expf(-x)); }
__device__ __forceinline__ float tanhft(float x) { return 1.0f - 2.0f / (__expf(2.0f * x) + 1.0f); }
__device__ __forceinline__ float b2f(unsigned short u) { return __uint_as_float((unsigned)u << 16); }

__device__ __forceinline__ void gload16(const void* g, void* l) {
    __builtin_amdgcn_global_load_lds((const __attribute__((address_space(1))) void*)g,
                                     (__attribute__((address_space(3))) void*)l, 16, 0, 0);
}

// ---------------------------------------------------------------------------
// Weight convert / transpose (one-shot).
// ---------------------------------------------------------------------------
__global__ void k_conv(const float* __restrict__ ef,   const float* __restrict__ ctx,
                       const float* __restrict__ Whi,  const float* __restrict__ Wci,
                       const float* __restrict__ Wih0, const float* __restrict__ Whh0,
                       const float* __restrict__ Wih1, const float* __restrict__ Whh1,
                       const float* __restrict__ Wo1,  const float* __restrict__ Wg1,
                       bf16* __restrict__ efb,  bf16* __restrict__ ctxb,
                       bf16* __restrict__ Wit,  bf16* __restrict__ Wt0,
                       bf16* __restrict__ Wt1,  bf16* __restrict__ Wo1t,
                       bf16* __restrict__ Wg1t)
{
    size_t tid = (size_t)blockIdx.x * blockDim.x + threadIdx.x;
    size_t gsz = (size_t)gridDim.x * blockDim.x;
    for (size_t i = tid; i < (size_t)Bsz * Dsz; i += gsz) {
        efb[i]  = __float2bfloat16(ef[i]);
        ctxb[i] = __float2bfloat16(ctx[i]);
    }
    for (size_t i = tid; i < 2048ull * 512; i += gsz) {     // Wt0[n][k] = W_hh0[k][n]
        size_t n = i >> 9, k = i & 511;
        Wt0[i] = __float2bfloat16(Whh0[k * 2048 + n]);
    }
    for (size_t i = tid; i < 2048ull * 1024; i += gsz) {    // Wt1[n][k] = [W_ih1; W_hh1][k][n]
        size_t n = i >> 10, k = i & 1023;
        Wt1[i] = __float2bfloat16(k < 512 ? Wih1[k * 2048 + n] : Whh1[(k - 512) * 2048 + n]);
    }
    for (size_t i = tid; i < 32ull * 512; i += gsz) {       // Wo1t/Wg1t[c][k]
        size_t c = i >> 9, k = i & 511;
        Wo1t[i] = __float2bfloat16(Wo1[k * 32 + c]);
        Wg1t[i] = __float2bfloat16(Wg1[k * 32 + c]);
    }
    for (size_t i = tid; i < 4096ull * 256; i += gsz) {     // Wit[n][k]: [Wh_init;Wc_init;W_ih0[1:]]^T
        size_t n = i >> 8, k = i & 255;
        float v = (n < 1024) ? Whi[k * 1024 + n]
                : (n < 2048) ? Wci[k * 1024 + (n - 1024)]
                             : Wih0[(1 + k) * 2048 + (n - 2048)];
        Wit[i] = __float2bfloat16(v);
    }
}

// ---------------------------------------------------------------------------
// Init GEMM: [h_init | c_init | ctx_gates]. ctx_gates stored [b][j][4 gates].
// ---------------------------------------------------------------------------
__global__ void __launch_bounds__(256)
k_init(const bf16* __restrict__ efb, const bf16* __restrict__ ctxb,
       const bf16* __restrict__ Wit,
       const float* __restrict__ bh,  const float* __restrict__ bc,
       const float* __restrict__ bi0, const float* __restrict__ bh0,
       bf16* __restrict__ h0, bf16* __restrict__ h1,
       float* __restrict__ c0, float* __restrict__ c1,
       bf16* __restrict__ ctxg)
{
    const int t = threadIdx.x, lane = t & 63, w = t >> 6;
    const int wr = w >> 1, wc = w & 1;
    const int lq = lane >> 4, ln = lane & 15;
    const int m0 = blockIdx.x * 128, n0 = blockIdx.y * 64;
    const bf16* A = (n0 < 2048) ? efb : ctxb;

    f32x4 zero = {0.f, 0.f, 0.f, 0.f};
    f32x4 acc[4][2];
#pragma unroll
    for (int r = 0; r < 4; ++r)
#pragma unroll
        for (int c = 0; c < 2; ++c) acc[r][c] = zero;

    for (int k0 = 0; k0 < 256; k0 += 32) {
        short8 af[4];
#pragma unroll
        for (int r = 0; r < 4; ++r)
            af[r] = *(const short8*)(A + (size_t)(m0 + wr * 64 + r * 16 + ln) * 256 + k0 + lq * 8);
#pragma unroll
        for (int c = 0; c < 2; ++c) {
            short8 bv = *(const short8*)(Wit + (size_t)(n0 + wc * 32 + c * 16 + ln) * 256 + k0 + lq * 8);
#pragma unroll
            for (int r = 0; r < 4; ++r)
                acc[r][c] = __builtin_amdgcn_mfma_f32_16x16x32_bf16(af[r], bv, acc[r][c], 0, 0, 0);
        }
    }
#pragma unroll
    for (int r = 0; r < 4; ++r)
#pragma unroll
        for (int c = 0; c < 2; ++c)
#pragma unroll
            for (int e = 0; e < 4; ++e) {
                int b = m0 + wr * 64 + r * 16 + lq * 4 + e;
                int n = n0 + wc * 32 + c * 16 + ln;
                float v = acc[r][c][e];
                if (n < 1024) {
                    v += bh[n];
                    if (n < 512) h0[(size_t)b * 512 + n]       = __float2bfloat16(v);
                    else         h1[(size_t)b * 512 + n - 512] = __float2bfloat16(v);
                } else if (n < 2048) {
                    int m = n - 1024; v += bc[m];
                    if (m < 512) c0[(size_t)b * 512 + m]       = v;
                    else         c1[(size_t)b * 512 + m - 512] = v;
                } else {
                    int j = n - 2048;
                    ctxg[(size_t)b * 2048 + (j & 511) * 4 + (j >> 9)] =
                        __float2bfloat16(v + bi0[j] + bh0[j]);
                }
            }
}

// ---------------------------------------------------------------------------
// intent head for 64 rows at m0 (4 waves; wave w: rows w*16..+16).
// ---------------------------------------------------------------------------
__device__ __forceinline__ void intent_head(
    const bf16* __restrict__ h, const bf16* __restrict__ W1t,
    const float* __restrict__ b1, const float* __restrict__ W2, float b2s,
    int m0, float* sitp, float* outp, int ostride)
{
    const int t = threadIdx.x, lane = t & 63, w = t >> 6;
    const int lq = lane >> 4, ln = lane & 15;
    f32x4 zero = {0.f, 0.f, 0.f, 0.f};
    f32x4 acc[2];
#pragma unroll
    for (int c = 0; c < 2; ++c) acc[c] = zero;

#pragma unroll
    for (int k0 = 0; k0 < 512; k0 += 32) {
        short8 av = *(const short8*)(h + (size_t)(m0 + w * 16 + ln) * 512 + k0 + lq * 8);
#pragma unroll
        for (int c = 0; c < 2; ++c) {
            short8 bv = *(const short8*)(W1t + (size_t)(c * 16 + ln) * 512 + k0 + lq * 8);
            acc[c] = __builtin_amdgcn_mfma_f32_16x16x32_bf16(av, bv, acc[c], 0, 0, 0);
        }
    }
#pragma unroll
    for (int e = 0; e < 4; ++e) {
        float v = 0.f;
#pragma unroll
        for (int c = 0; c < 2; ++c) {
            int col = c * 16 + ln;
            v += fmaxf(acc[c][e] + b1[col], 0.f) * W2[col];
        }
        v += __shfl_xor(v, 1);
        v += __shfl_xor(v, 2);
        v += __shfl_xor(v, 4);
        v += __shfl_xor(v, 8);
        int row = w * 16 + lq * 4 + e;                 // 0..63
        if (ln == 0) {
            float p = sigf(v + b2s);
            if (sitp) sitp[row] = p;
            if (outp) outp[(size_t)(m0 + row) * ostride] = p;
        }
    }
}

// ---------------------------------------------------------------------------
// Staging: tile (64 rows x 32 K) of A and (4g x 32 n x 32 K) of B into LDS.
// 4 chunks/row; swizzle slot = kc ^ ((row>>1)&3)  -> 2-way bank alias (free).
// A: 1 chunk/thread, B: 2 chunks/thread.
// ---------------------------------------------------------------------------
template <int L0>
__device__ __forceinline__ void stage(const bf16* __restrict__ hA, const bf16* __restrict__ hB,
                                      const bf16* __restrict__ Wt,
                                      int m0, int j0, int k0, bf16* Ab, bf16* Bb, int t)
{
    constexpr int KW = L0 ? 512 : 1024;
    {
        int row = t >> 2, slot = t & 3;
        int kk = k0 + ((slot ^ ((row >> 1) & 3)) << 3);
        const bf16* src;
        if (L0) src = hA + (size_t)(m0 + row) * Hsz + kk;
        else    src = (kk < 512) ? hA + (size_t)(m0 + row) * Hsz + kk
                                 : hB + (size_t)(m0 + row) * Hsz + (kk - 512);
        gload16(src, (char*)Ab + (size_t)t * 16);
    }
#pragma unroll
    for (int i = 0; i < 2; ++i) {
        int f = i * 256 + t;
        int brow = f >> 2, slot = f & 3;               // brow = g*32+n, 0..127
        int kc = slot ^ ((brow >> 1) & 3);
        gload16(Wt + (size_t)((brow >> 5) * 512 + j0 + (brow & 31)) * KW + k0 + kc * 8,
                (char*)Bb + (size_t)f * 16);
    }
}

// one 32-K LDS tile of MFMA work (4 gates x 2 row-frags)
__device__ __forceinline__ void mfma_tile(const bf16* Ab, const bf16* Bb,
                                          int wr, int wc, int lq, int ln,
                                          f32x4 (&acc)[4][2])
{
    short8 af[2], bfr[4];
#pragma unroll
    for (int r = 0; r < 2; ++r) {
        int row = wr * 32 + r * 16 + ln;
        int slot = lq ^ ((row >> 1) & 3);
        af[r] = *(const short8*)(Ab + ((size_t)row * 4 + slot) * 8);
    }
#pragma unroll
    for (int g = 0; g < 4; ++g) {
        int brow = g * 32 + wc * 16 + ln;
        int slot = lq ^ ((brow >> 1) & 3);
        bfr[g] = *(const short8*)(Bb + ((size_t)brow * 4 + slot) * 8);
    }
#pragma unroll
    for (int g = 0; g < 4; ++g)
#pragma unroll
        for (int r = 0; r < 2; ++r)
            acc[g][r] = __builtin_amdgcn_mfma_f32_16x16x32_bf16(af[r], bfr[g], acc[g][r], 0, 0, 0);
}

// ---------------------------------------------------------------------------
// Fused gates GEMM + LSTM cell (+ intent head for L0). 64 rows x 32 gate-cols
// x 4 gates per WG; BK=32 double-buffered; 4 WGs/CU.
// ---------------------------------------------------------------------------
template <int L0>
__global__ void __launch_bounds__(256, 4)
k_gates(const bf16* __restrict__ hA, const bf16* __restrict__ hB,
        const bf16* __restrict__ Wt,
        const bf16* __restrict__ ctxg, const float* __restrict__ ii,
        const bf16* __restrict__ h1prev,
        const float* __restrict__ w0row,
        const float* __restrict__ b1, const float* __restrict__ b2,
        const bf16* __restrict__ Wo1t, const float* __restrict__ bo1,
        const float* __restrict__ Wo2, const float* __restrict__ bo2,
        float* __restrict__ cbuf, bf16* __restrict__ hout,
        float* __restrict__ outp, int step)
{
    constexpr int KW = L0 ? 512 : 1024;
    constexpr int NT = KW / 32;
    __shared__ __align__(16) char lds[24576];
    __shared__ float sitp[64];
    bf16* A0 = (bf16*)lds;                    // 4 KB
    bf16* A1 = (bf16*)(lds + 4096);           // 4 KB
    bf16* B0 = (bf16*)(lds + 8192);           // 8 KB
    bf16* B1 = (bf16*)(lds + 16384);          // 8 KB

    const int t = threadIdx.x, lane = t & 63, w = t >> 6;
    const int wr = w >> 1, wc = w & 1, lq = lane >> 4, ln = lane & 15;
    const int j0 = blockIdx.x * 32, m0 = blockIdx.y * 64;

    stage<L0>(hA, hB, Wt, m0, j0, 0, A0, B0, t);    // tile 0 in flight

    float sreg[8];
    if (L0) {
        if (step == 0) {
            if (t < 64) sitp[t] = ii[m0 + t];
        } else {
            intent_head(h1prev, Wo1t, bo1, Wo2, bo2[0], m0, sitp,
                        (blockIdx.x == 0) ? outp + (step - 1) : nullptr, Tsz);
        }
    }
    __syncthreads();                                  // tile 0 landed (+ sitp)
    if (L0) {
#pragma unroll
        for (int r = 0; r < 2; ++r)
#pragma unroll
            for (int e = 0; e < 4; ++e)
                sreg[r * 4 + e] = sitp[wr * 32 + r * 16 + lq * 4 + e];
    }

    f32x4 zero = {0.f, 0.f, 0.f, 0.f};
    f32x4 acc[4][2];
#pragma unroll
    for (int g = 0; g < 4; ++g)
#pragma unroll
        for (int r = 0; r < 2; ++r) acc[g][r] = zero;

#pragma unroll 2
    for (int kt = 0; kt < NT; ++kt) {
        if (kt + 1 < NT)
            stage<L0>(hA, hB, Wt, m0, j0, (kt + 1) * 32,
                      (kt & 1) ? A0 : A1, (kt & 1) ? B0 : B1, t);
        mfma_tile((kt & 1) ? A1 : A0, (kt & 1) ? B1 : B0, wr, wc, lq, ln, acc);
        if (kt + 1 < NT) __syncthreads();             // next tile landed; cur read
    }

    // ---- fused LSTM cell epilogue. C/D frag: col=lane&15, row=(lane>>4)*4+reg
    const int jl = j0 + wc * 16 + ln;
    float addc[4];
#pragma unroll
    for (int g = 0; g < 4; ++g)
        addc[g] = L0 ? w0row[g * 512 + jl] : (b1[g * 512 + jl] + b2[g * 512 + jl]);

#pragma unroll
    for (int r = 0; r < 2; ++r)
#pragma unroll
        for (int e = 0; e < 4; ++e) {
            int b = m0 + wr * 32 + r * 16 + lq * 4 + e;
            float pre[4];
#pragma unroll
            for (int g = 0; g < 4; ++g) pre[g] = acc[g][r][e];
            if (L0) {
                float it = sreg[r * 4 + e];
                us4 cg = *(const us4*)((const unsigned short*)ctxg + (size_t)b * 2048 + jl * 4);
#pragma unroll
                for (int g = 0; g < 4; ++g) pre[g] += b2f(cg[g]) + it * addc[g];
            } else {
#pragma unroll
                for (int g = 0; g < 4; ++g) pre[g] += addc[g];
            }
            float ig = sigf(pre[0]), fg = sigf(pre[1]);
            float gg = tanhft(pre[2]), og = sigf(pre[3]);
            size_t idx = (size_t)b * Hsz + jl;
            float cn = fg * cbuf[idx] + ig * gg;
            cbuf[idx] = cn;
            hout[idx] = __float2bfloat16(og * tanhft(cn));
        }
}

// ---------------------------------------------------------------------------
// standalone head (final step intent + global head), 64 rows/block
// ---------------------------------------------------------------------------
__global__ void __launch_bounds__(256)
k_intent(const bf16* __restrict__ h, const bf16* __restrict__ W1t,
         const float* __restrict__ bias1, const float* __restrict__ W2,
         const float* __restrict__ bias2,
         float* __restrict__ outp, int ostride)
{
    intent_head(h, W1t, bias1, W2, bias2[0], blockIdx.x * 64, nullptr, outp, ostride);
}

// ---------------------------------------------------------------------------
extern "C" void kernel_launch(void* const* d_in, const int* in_sizes, int n_in,
                              void* d_out, int out_size, void* d_ws, size_t ws_size,
                              hipStream_t stream)
{
    const float* ef   = (const float*)d_in[0];
    const float* ctx  = (const float*)d_in[1];
    const float* ii   = (const float*)d_in[2];
    const float* Whi  = (const float*)d_in[3];
    const float* bh   = (const float*)d_in[4];
    const float* Wci  = (const float*)d_in[5];
    const float* bc   = (const float*)d_in[6];
    const float* Wih0 = (const float*)d_in[7];
    const float* Whh0 = (const float*)d_in[8];
    const float* bi0  = (const float*)d_in[9];
    const float* bh0  = (const float*)d_in[10];
    const float* Wih1 = (const float*)d_in[11];
    const float* Whh1 = (const float*)d_in[12];
    const float* bi1  = (const float*)d_in[13];
    const float* bh1  = (const float*)d_in[14];
    const float* Wo1  = (const float*)d_in[15];
    const float* bo1  = (const float*)d_in[16];
    const float* Wo2  = (const float*)d_in[17];
    const float* bo2  = (const float*)d_in[18];
    const float* Wg1  = (const float*)d_in[19];
    const float* bg1  = (const float*)d_in[20];
    const float* Wg2  = (const float*)d_in[21];
    const float* bg2  = (const float*)d_in[22];
    float* out = (float*)d_out;

    char* ws = (char*)d_ws;
    size_t off = 0;
    auto take = [&](size_t bytes) -> char* {
        char* pp = ws + off;
        off += (bytes + 255) & ~(size_t)255;
        return pp;
    };
    bf16* Wt0    = (bf16*)take(2048ull * 512 * 2);
    bf16* Wt1    = (bf16*)take(2048ull * 1024 * 2);
    bf16* Wo1t   = (bf16*)take(32ull * 512 * 2);
    bf16* Wg1t   = (bf16*)take(32ull * 512 * 2);
    bf16* Wit    = (bf16*)take(4096ull * 256 * 2);
    bf16* efb    = (bf16*)take((size_t)Bsz * Dsz * 2);
    bf16* ctxb   = (bf16*)take((size_t)Bsz * Dsz * 2);
    bf16* h0x    = (bf16*)take((size_t)Bsz * Hsz * 2);
    bf16* h0y    = (bf16*)take((size_t)Bsz * Hsz * 2);
    bf16* h1x    = (bf16*)take((size_t)Bsz * Hsz * 2);
    bf16* h1y    = (bf16*)take((size_t)Bsz * Hsz * 2);
    float* c0    = (float*)take((size_t)Bsz * Hsz * 4);
    float* c1    = (float*)take((size_t)Bsz * Hsz * 4);
    bf16* ctxg   = (bf16*)take((size_t)Bsz * 2048 * 2);
    (void)ws_size; (void)in_sizes; (void)n_in; (void)out_size;

    k_conv<<<2048, 256, 0, stream>>>(ef, ctx, Whi, Wci, Wih0, Whh0, Wih1, Whh1, Wo1, Wg1,
                                     efb, ctxb, Wit, Wt0, Wt1, Wo1t, Wg1t);
    k_init<<<dim3(32, 64), 256, 0, stream>>>(efb, ctxb, Wit, bh, bc, bi0, bh0,
                                             h0x, h1x, c0, c1, ctxg);

    for (int s = 0; s < Tsz; ++s) {
        int p = s & 1;
        const bf16* h0in  = p ? h0y : h0x;
        bf16*       h0out = p ? h0x : h0y;
        const bf16* h1in  = p ? h1y : h1x;
        bf16*       h1out = p ? h1x : h1y;
        k_gates<1><<<dim3(16, 64), 256, 0, stream>>>(
            h0in, nullptr, Wt0, ctxg, ii, h1in, Wih0, nullptr, nullptr,
            Wo1t, bo1, Wo2, bo2, c0, h0out, out, s);
        k_gates<0><<<dim3(16, 64), 256, 0, stream>>>(
            h0out, h1in, Wt1, nullptr, nullptr, nullptr, nullptr, bi1, bh1,
            nullptr, nullptr, nullptr, nullptr, c1, h1out, nullptr, s);
    }
    // s=44 wrote h1y; remaining outputs: step col 44 + global head
    k_intent<<<64, 256, 0, stream>>>(h1y, Wo1t, bo1, Wo2, bo2, out + 44, Tsz);
    k_intent<<<64, 256, 0, stream>>>(h1y, Wg1t, bg1, Wg2, bg2, out + (size_t)Bsz * Tsz, 1);
}

// Round 6
// 2965.226 us; speedup vs baseline: 3.9549x; 1.1561x over previous
//
#include <hip/hip_runtime.h>
#include <hip/hip_bf16.h>

#define Bsz 4096
#define Dsz 256
#define Hsz 512
#define Tsz 45

typedef __attribute__((ext_vector_type(8))) short short8;
typedef __attribute__((ext_vector_type(4))) float f32x4;
typedef __attribute__((ext_vector_type(4))) unsigned short us4;
using bf16 = __hip_bfloat16;

__device__ __forceinline__ float sigf(float x)   { return 1.0f / (1.0f + __expf(-x)); }
__device__ __forceinline__ float tanhft(float x) { return 1.0f - 2.0f / (__expf(2.0f * x) + 1.0f); }
__device__ __forceinline__ float b2f(unsigned short u) { return __uint_as_float((unsigned)u << 16); }

__device__ __forceinline__ void gload16(const void* g, void* l) {
    __builtin_amdgcn_global_load_lds((const __attribute__((address_space(1))) void*)g,
                                     (__attribute__((address_space(3))) void*)l, 16, 0, 0);
}

// ---------------------------------------------------------------------------
// Weight convert / transpose (one-shot).
// ---------------------------------------------------------------------------
__global__ void k_conv(const float* __restrict__ ef,   const float* __restrict__ ctx,
                       const float* __restrict__ Whi,  const float* __restrict__ Wci,
                       const float* __restrict__ Wih0, const float* __restrict__ Whh0,
                       const float* __restrict__ Wih1, const float* __restrict__ Whh1,
                       const float* __restrict__ Wo1,  const float* __restrict__ Wg1,
                       bf16* __restrict__ efb,  bf16* __restrict__ ctxb,
                       bf16* __restrict__ Wit,  bf16* __restrict__ Wt0,
                       bf16* __restrict__ Wt1,  bf16* __restrict__ Wo1t,
                       bf16* __restrict__ Wg1t)
{
    size_t tid = (size_t)blockIdx.x * blockDim.x + threadIdx.x;
    size_t gsz = (size_t)gridDim.x * blockDim.x;
    for (size_t i = tid; i < (size_t)Bsz * Dsz; i += gsz) {
        efb[i]  = __float2bfloat16(ef[i]);
        ctxb[i] = __float2bfloat16(ctx[i]);
    }
    for (size_t i = tid; i < 2048ull * 512; i += gsz) {     // Wt0[n][k] = W_hh0[k][n]
        size_t n = i >> 9, k = i & 511;
        Wt0[i] = __float2bfloat16(Whh0[k * 2048 + n]);
    }
    for (size_t i = tid; i < 2048ull * 1024; i += gsz) {    // Wt1[n][k] = [W_ih1; W_hh1][k][n]
        size_t n = i >> 10, k = i & 1023;
        Wt1[i] = __float2bfloat16(k < 512 ? Wih1[k * 2048 + n] : Whh1[(k - 512) * 2048 + n]);
    }
    for (size_t i = tid; i < 32ull * 512; i += gsz) {       // Wo1t/Wg1t[c][k]
        size_t c = i >> 9, k = i & 511;
        Wo1t[i] = __float2bfloat16(Wo1[k * 32 + c]);
        Wg1t[i] = __float2bfloat16(Wg1[k * 32 + c]);
    }
    for (size_t i = tid; i < 4096ull * 256; i += gsz) {     // Wit[n][k]: [Wh_init;Wc_init;W_ih0[1:]]^T
        size_t n = i >> 8, k = i & 255;
        float v = (n < 1024) ? Whi[k * 1024 + n]
                : (n < 2048) ? Wci[k * 1024 + (n - 1024)]
                             : Wih0[(1 + k) * 2048 + (n - 2048)];
        Wit[i] = __float2bfloat16(v);
    }
}

// ---------------------------------------------------------------------------
// Init GEMM: [h_init | c_init | ctx_gates]. ctx_gates stored [b][j][4 gates].
// ---------------------------------------------------------------------------
__global__ void __launch_bounds__(256)
k_init(const bf16* __restrict__ efb, const bf16* __restrict__ ctxb,
       const bf16* __restrict__ Wit,
       const float* __restrict__ bh,  const float* __restrict__ bc,
       const float* __restrict__ bi0, const float* __restrict__ bh0,
       bf16* __restrict__ h0, bf16* __restrict__ h1,
       float* __restrict__ c0, float* __restrict__ c1,
       bf16* __restrict__ ctxg)
{
    const int t = threadIdx.x, lane = t & 63, w = t >> 6;
    const int wr = w >> 1, wc = w & 1;
    const int lq = lane >> 4, ln = lane & 15;
    const int m0 = blockIdx.x * 128, n0 = blockIdx.y * 64;
    const bf16* A = (n0 < 2048) ? efb : ctxb;

    f32x4 zero = {0.f, 0.f, 0.f, 0.f};
    f32x4 acc[4][2];
#pragma unroll
    for (int r = 0; r < 4; ++r)
#pragma unroll
        for (int c = 0; c < 2; ++c) acc[r][c] = zero;

    for (int k0 = 0; k0 < 256; k0 += 32) {
        short8 af[4];
#pragma unroll
        for (int r = 0; r < 4; ++r)
            af[r] = *(const short8*)(A + (size_t)(m0 + wr * 64 + r * 16 + ln) * 256 + k0 + lq * 8);
#pragma unroll
        for (int c = 0; c < 2; ++c) {
            short8 bv = *(const short8*)(Wit + (size_t)(n0 + wc * 32 + c * 16 + ln) * 256 + k0 + lq * 8);
#pragma unroll
            for (int r = 0; r < 4; ++r)
                acc[r][c] = __builtin_amdgcn_mfma_f32_16x16x32_bf16(af[r], bv, acc[r][c], 0, 0, 0);
        }
    }
#pragma unroll
    for (int r = 0; r < 4; ++r)
#pragma unroll
        for (int c = 0; c < 2; ++c)
#pragma unroll
            for (int e = 0; e < 4; ++e) {
                int b = m0 + wr * 64 + r * 16 + lq * 4 + e;
                int n = n0 + wc * 32 + c * 16 + ln;
                float v = acc[r][c][e];
                if (n < 1024) {
                    v += bh[n];
                    if (n < 512) h0[(size_t)b * 512 + n]       = __float2bfloat16(v);
                    else         h1[(size_t)b * 512 + n - 512] = __float2bfloat16(v);
                } else if (n < 2048) {
                    int m = n - 1024; v += bc[m];
                    if (m < 512) c0[(size_t)b * 512 + m]       = v;
                    else         c1[(size_t)b * 512 + m - 512] = v;
                } else {
                    int j = n - 2048;
                    ctxg[(size_t)b * 2048 + (j & 511) * 4 + (j >> 9)] =
                        __float2bfloat16(v + bi0[j] + bh0[j]);
                }
            }
}

// ---------------------------------------------------------------------------
// intent head for 128 rows at m0 (4 waves; wave w: rows w*32..+32).
// ---------------------------------------------------------------------------
__device__ __forceinline__ void intent_head(
    const bf16* __restrict__ h, const bf16* __restrict__ W1t,
    const float* __restrict__ b1, const float* __restrict__ W2, float b2s,
    int m0, float* sitp, float* outp, int ostride)
{
    const int t = threadIdx.x, lane = t & 63, w = t >> 6;
    const int lq = lane >> 4, ln = lane & 15;
    f32x4 zero = {0.f, 0.f, 0.f, 0.f};
    f32x4 acc[2][2];
#pragma unroll
    for (int r = 0; r < 2; ++r)
#pragma unroll
        for (int c = 0; c < 2; ++c) acc[r][c] = zero;

#pragma unroll
    for (int k0 = 0; k0 < 512; k0 += 32) {
        short8 av[2], bv[2];
#pragma unroll
        for (int r = 0; r < 2; ++r)
            av[r] = *(const short8*)(h + (size_t)(m0 + w * 32 + r * 16 + ln) * 512 + k0 + lq * 8);
#pragma unroll
        for (int c = 0; c < 2; ++c)
            bv[c] = *(const short8*)(W1t + (size_t)(c * 16 + ln) * 512 + k0 + lq * 8);
#pragma unroll
        for (int r = 0; r < 2; ++r)
#pragma unroll
            for (int c = 0; c < 2; ++c)
                acc[r][c] = __builtin_amdgcn_mfma_f32_16x16x32_bf16(av[r], bv[c], acc[r][c], 0, 0, 0);
    }
#pragma unroll
    for (int r = 0; r < 2; ++r)
#pragma unroll
        for (int e = 0; e < 4; ++e) {
            float v = 0.f;
#pragma unroll
            for (int c = 0; c < 2; ++c) {
                int col = c * 16 + ln;
                v += fmaxf(acc[r][c][e] + b1[col], 0.f) * W2[col];
            }
            v += __shfl_xor(v, 1);
            v += __shfl_xor(v, 2);
            v += __shfl_xor(v, 4);
            v += __shfl_xor(v, 8);
            int row = w * 32 + r * 16 + lq * 4 + e;          // 0..127
            if (ln == 0) {
                float p = sigf(v + b2s);
                if (sitp) sitp[row] = p;
                if (outp) outp[(size_t)(m0 + row) * ostride] = p;
            }
        }
}

// ---------------------------------------------------------------------------
// Staging: one BK=32 tile (A: 128 rows x 32k = 8 KB; B: 4g x 32n x 32k = 8 KB)
// into one 16 KB ring buffer. 4 chunks/row, swizzle slot = kc ^ ((row>>1)&3)
// pre-applied on the GLOBAL side (LDS dest stays linear). 4 loads/thread.
// ---------------------------------------------------------------------------
template <int L0>
__device__ __forceinline__ void stage(const bf16* __restrict__ hA, const bf16* __restrict__ hB,
                                      const bf16* __restrict__ Wt,
                                      int m0, int j0, int k0, char* buf, int t)
{
    constexpr int KW = L0 ? 512 : 1024;
#pragma unroll
    for (int i = 0; i < 2; ++i) {
        int f = i * 256 + t;
        int row = f >> 2, slot = f & 3;
        int kk = k0 + ((slot ^ ((row >> 1) & 3)) << 3);
        const bf16* src;
        if (L0) src = hA + (size_t)(m0 + row) * Hsz + kk;
        else    src = (kk < 512) ? hA + (size_t)(m0 + row) * Hsz + kk
                                 : hB + (size_t)(m0 + row) * Hsz + (kk - 512);
        gload16(src, buf + (size_t)f * 16);
    }
#pragma unroll
    for (int i = 0; i < 2; ++i) {
        int f = i * 256 + t;
        int brow = f >> 2, slot = f & 3;               // brow = g*32+n
        int kc = slot ^ ((brow >> 1) & 3);
        gload16(Wt + (size_t)((brow >> 5) * 512 + j0 + (brow & 31)) * KW + k0 + kc * 8,
                buf + 8192 + (size_t)f * 16);
    }
}

// one BK=32 tile of MFMA work: 4 gates x 4 row-frags = 16 MFMA
__device__ __forceinline__ void mfma_tile(const char* buf,
                                          int wr, int wc, int lq, int ln,
                                          f32x4 (&acc)[4][4])
{
    const bf16* Ab = (const bf16*)buf;
    const bf16* Bb = (const bf16*)(buf + 8192);
    short8 af[4], bfr[4];
#pragma unroll
    for (int r = 0; r < 4; ++r) {
        int row = wr * 64 + r * 16 + ln;
        int slot = lq ^ ((row >> 1) & 3);
        af[r] = *(const short8*)(Ab + ((size_t)row * 4 + slot) * 8);
    }
#pragma unroll
    for (int g = 0; g < 4; ++g) {
        int brow = g * 32 + wc * 16 + ln;
        int slot = lq ^ ((brow >> 1) & 3);
        bfr[g] = *(const short8*)(Bb + ((size_t)brow * 4 + slot) * 8);
    }
#pragma unroll
    for (int g = 0; g < 4; ++g)
#pragma unroll
        for (int r = 0; r < 4; ++r)
            acc[g][r] = __builtin_amdgcn_mfma_f32_16x16x32_bf16(af[r], bfr[g], acc[g][r], 0, 0, 0);
}

#define WAIT_VM(N) asm volatile("s_waitcnt vmcnt(" #N ")" ::: "memory")

// ---------------------------------------------------------------------------
// Fused gates GEMM + LSTM cell (+ intent head for L0). 128 rows x 128 gates
// per WG; depth-3 pipelined ring-4 LDS (BK=32), counted vmcnt, raw barriers.
// XCD-bijective swizzle: xcd = bid&7 owns jblks {2*xcd, 2*xcd+1}.
// ---------------------------------------------------------------------------
template <int L0>
__global__ void __launch_bounds__(256, 2)
k_gates(const bf16* __restrict__ hA, const bf16* __restrict__ hB,
        const bf16* __restrict__ Wt,
        const bf16* __restrict__ ctxg, const float* __restrict__ ii,
        const bf16* __restrict__ h1prev,
        const float* __restrict__ w0row,
        const float* __restrict__ b1, const float* __restrict__ b2,
        const bf16* __restrict__ Wo1t, const float* __restrict__ bo1,
        const float* __restrict__ Wo2, const float* __restrict__ bo2,
        float* __restrict__ cbuf, bf16* __restrict__ hout,
        float* __restrict__ outp, int step)
{
    constexpr int KW = L0 ? 512 : 1024;
    constexpr int NT = KW / 32;
    __shared__ __align__(16) char lds[65536];          // 4 ring buffers x 16 KB
    __shared__ float sitp[128];

    const int t = threadIdx.x, lane = t & 63, w = t >> 6;
    const int wr = w >> 1, wc = w & 1, lq = lane >> 4, ln = lane & 15;
    const int bid = blockIdx.x;
    const int xcd = bid & 7, idx = bid >> 3;
    const int jblk = xcd * 2 + (idx >> 5), mblk = idx & 31;
    const int j0 = jblk * 32, m0 = mblk * 128;

    // prologue: 3 stage tiles in flight (12 loads/thread)
    stage<L0>(hA, hB, Wt, m0, j0, 0,  lds,         t);
    stage<L0>(hA, hB, Wt, m0, j0, 32, lds + 16384, t);
    stage<L0>(hA, hB, Wt, m0, j0, 64, lds + 32768, t);

    float sreg[16];
    if (L0) {
        // intent head overlaps the in-flight stages
        if (step == 0) {
            if (t < 128) sitp[t] = ii[m0 + t];
        } else {
            intent_head(h1prev, Wo1t, bo1, Wo2, bo2[0], m0, sitp,
                        (jblk == 0) ? outp + (step - 1) : nullptr, Tsz);
        }
        asm volatile("s_waitcnt lgkmcnt(0)" ::: "memory");
        __builtin_amdgcn_s_barrier();                  // sitp visible to all waves
#pragma unroll
        for (int r = 0; r < 4; ++r)
#pragma unroll
            for (int e = 0; e < 4; ++e)
                sreg[r * 4 + e] = sitp[wr * 64 + r * 16 + lq * 4 + e];
    }

    f32x4 zero = {0.f, 0.f, 0.f, 0.f};
    f32x4 acc[4][4];
#pragma unroll
    for (int g = 0; g < 4; ++g)
#pragma unroll
        for (int r = 0; r < 4; ++r) acc[g][r] = zero;

    // main pipelined loop: wait own stage-kt loads (8 younger stay in flight),
    // barrier (=> whole buffer landed), compute, issue stage kt+3.
#pragma unroll 4
    for (int kt = 0; kt < NT - 3; ++kt) {
        WAIT_VM(8);
        __builtin_amdgcn_s_barrier();
        mfma_tile(lds + (size_t)(kt & 3) * 16384, wr, wc, lq, ln, acc);
        stage<L0>(hA, hB, Wt, m0, j0, (kt + 3) * 32, lds + (size_t)((kt + 3) & 3) * 16384, t);
    }
    WAIT_VM(8);
    __builtin_amdgcn_s_barrier();
    mfma_tile(lds + (size_t)((NT - 3) & 3) * 16384, wr, wc, lq, ln, acc);
    WAIT_VM(4);
    __builtin_amdgcn_s_barrier();
    mfma_tile(lds + (size_t)((NT - 2) & 3) * 16384, wr, wc, lq, ln, acc);
    WAIT_VM(0);
    __builtin_amdgcn_s_barrier();
    mfma_tile(lds + (size_t)((NT - 1) & 3) * 16384, wr, wc, lq, ln, acc);

    // ---- fused LSTM cell epilogue. C/D frag: col=lane&15, row=(lane>>4)*4+reg
    const int jl = j0 + wc * 16 + ln;
    float addc[4];
#pragma unroll
    for (int g = 0; g < 4; ++g)
        addc[g] = L0 ? w0row[g * 512 + jl] : (b1[g * 512 + jl] + b2[g * 512 + jl]);

#pragma unroll
    for (int r = 0; r < 4; ++r)
#pragma unroll
        for (int e = 0; e < 4; ++e) {
            int b = m0 + wr * 64 + r * 16 + lq * 4 + e;
            float pre[4];
#pragma unroll
            for (int g = 0; g < 4; ++g) pre[g] = acc[g][r][e];
            if (L0) {
                float it = sreg[r * 4 + e];
                us4 cg = *(const us4*)((const unsigned short*)ctxg + (size_t)b * 2048 + jl * 4);
#pragma unroll
                for (int g = 0; g < 4; ++g) pre[g] += b2f(cg[g]) + it * addc[g];
            } else {
#pragma unroll
                for (int g = 0; g < 4; ++g) pre[g] += addc[g];
            }
            float ig = sigf(pre[0]), fg = sigf(pre[1]);
            float gg = tanhft(pre[2]), og = sigf(pre[3]);
            size_t idxb = (size_t)b * Hsz + jl;
            float cn = fg * cbuf[idxb] + ig * gg;
            cbuf[idxb] = cn;
            hout[idxb] = __float2bfloat16(og * tanhft(cn));
        }
}

// ---------------------------------------------------------------------------
// standalone head (final step intent + global head), 128 rows/block
// ---------------------------------------------------------------------------
__global__ void __launch_bounds__(256)
k_intent(const bf16* __restrict__ h, const bf16* __restrict__ W1t,
         const float* __restrict__ bias1, const float* __restrict__ W2,
         const float* __restrict__ bias2,
         float* __restrict__ outp, int ostride)
{
    intent_head(h, W1t, bias1, W2, bias2[0], blockIdx.x * 128, nullptr, outp, ostride);
}

// ---------------------------------------------------------------------------
extern "C" void kernel_launch(void* const* d_in, const int* in_sizes, int n_in,
                              void* d_out, int out_size, void* d_ws, size_t ws_size,
                              hipStream_t stream)
{
    const float* ef   = (const float*)d_in[0];
    const float* ctx  = (const float*)d_in[1];
    const float* ii   = (const float*)d_in[2];
    const float* Whi  = (const float*)d_in[3];
    const float* bh   = (const float*)d_in[4];
    const float* Wci  = (const float*)d_in[5];
    const float* bc   = (const float*)d_in[6];
    const float* Wih0 = (const float*)d_in[7];
    const float* Whh0 = (const float*)d_in[8];
    const float* bi0  = (const float*)d_in[9];
    const float* bh0  = (const float*)d_in[10];
    const float* Wih1 = (const float*)d_in[11];
    const float* Whh1 = (const float*)d_in[12];
    const float* bi1  = (const float*)d_in[13];
    const float* bh1  = (const float*)d_in[14];
    const float* Wo1  = (const float*)d_in[15];
    const float* bo1  = (const float*)d_in[16];
    const float* Wo2  = (const float*)d_in[17];
    const float* bo2  = (const float*)d_in[18];
    const float* Wg1  = (const float*)d_in[19];
    const float* bg1  = (const float*)d_in[20];
    const float* Wg2  = (const float*)d_in[21];
    const float* bg2  = (const float*)d_in[22];
    float* out = (float*)d_out;

    char* ws = (char*)d_ws;
    size_t off = 0;
    auto take = [&](size_t bytes) -> char* {
        char* pp = ws + off;
        off += (bytes + 255) & ~(size_t)255;
        return pp;
    };
    bf16* Wt0    = (bf16*)take(2048ull * 512 * 2);
    bf16* Wt1    = (bf16*)take(2048ull * 1024 * 2);
    bf16* Wo1t   = (bf16*)take(32ull * 512 * 2);
    bf16* Wg1t   = (bf16*)take(32ull * 512 * 2);
    bf16* Wit    = (bf16*)take(4096ull * 256 * 2);
    bf16* efb    = (bf16*)take((size_t)Bsz * Dsz * 2);
    bf16* ctxb   = (bf16*)take((size_t)Bsz * Dsz * 2);
    bf16* h0x    = (bf16*)take((size_t)Bsz * Hsz * 2);
    bf16* h0y    = (bf16*)take((size_t)Bsz * Hsz * 2);
    bf16* h1x    = (bf16*)take((size_t)Bsz * Hsz * 2);
    bf16* h1y    = (bf16*)take((size_t)Bsz * Hsz * 2);
    float* c0    = (float*)take((size_t)Bsz * Hsz * 4);
    float* c1    = (float*)take((size_t)Bsz * Hsz * 4);
    bf16* ctxg   = (bf16*)take((size_t)Bsz * 2048 * 2);
    (void)ws_size; (void)in_sizes; (void)n_in; (void)out_size;

    k_conv<<<2048, 256, 0, stream>>>(ef, ctx, Whi, Wci, Wih0, Whh0, Wih1, Whh1, Wo1, Wg1,
                                     efb, ctxb, Wit, Wt0, Wt1, Wo1t, Wg1t);
    k_init<<<dim3(32, 64), 256, 0, stream>>>(efb, ctxb, Wit, bh, bc, bi0, bh0,
                                             h0x, h1x, c0, c1, ctxg);

    for (int s = 0; s < Tsz; ++s) {
        int p = s & 1;
        const bf16* h0in  = p ? h0y : h0x;
        bf16*       h0out = p ? h0x : h0y;
        const bf16* h1in  = p ? h1y : h1x;
        bf16*       h1out = p ? h1x : h1y;
        k_gates<1><<<512, 256, 0, stream>>>(
            h0in, nullptr, Wt0, ctxg, ii, h1in, Wih0, nullptr, nullptr,
            Wo1t, bo1, Wo2, bo2, c0, h0out, out, s);
        k_gates<0><<<512, 256, 0, stream>>>(
            h0out, h1in, Wt1, nullptr, nullptr, nullptr, nullptr, bi1, bh1,
            nullptr, nullptr, nullptr, nullptr, c1, h1out, nullptr, s);
    }
    // s=44 wrote h1y; remaining outputs: step col 44 + global head
    k_intent<<<32, 256, 0, stream>>>(h1y, Wo1t, bo1, Wo2, bo2, out + 44, Tsz);
    k_intent<<<32, 256, 0, stream>>>(h1y, Wg1t, bg1, Wg2, bg2, out + (size_t)Bsz * Tsz, 1);
}

// Round 7
// 2724.064 us; speedup vs baseline: 4.3050x; 1.0885x over previous
//
#include <hip/hip_runtime.h>
#include <hip/hip_bf16.h>

#define Bsz 4096
#define Dsz 256
#define Hsz 512
#define Tsz 45

typedef __attribute__((ext_vector_type(8))) short short8;
typedef __attribute__((ext_vector_type(4))) float f32x4;
typedef __attribute__((ext_vector_type(4))) unsigned short us4;
using bf16 = __hip_bfloat16;

__device__ __forceinline__ float sigf(float x)   { return 1.0f / (1.0f + __expf(-x)); }
__device__ __forceinline__ float tanhft(float x) { return 1.0f - 2.0f / (__expf(2.0f * x) + 1.0f); }
__device__ __forceinline__ float b2f(unsigned short u) { return __uint_as_float((unsigned)u << 16); }

__device__ __forceinline__ void gload16(const void* g, void* l) {
    __builtin_amdgcn_global_load_lds((const __attribute__((address_space(1))) void*)g,
                                     (__attribute__((address_space(3))) void*)l, 16, 0, 0);
}

// ---------------------------------------------------------------------------
// Weight convert / transpose (one-shot).
// ---------------------------------------------------------------------------
__global__ void k_conv(const float* __restrict__ ef,   const float* __restrict__ ctx,
                       const float* __restrict__ Whi,  const float* __restrict__ Wci,
                       const float* __restrict__ Wih0, const float* __restrict__ Whh0,
                       const float* __restrict__ Wih1, const float* __restrict__ Whh1,
                       const float* __restrict__ Wo1,  const float* __restrict__ Wg1,
                       bf16* __restrict__ efb,  bf16* __restrict__ ctxb,
                       bf16* __restrict__ Wit,  bf16* __restrict__ Wt0,
                       bf16* __restrict__ Wt1,  bf16* __restrict__ Wo1t,
                       bf16* __restrict__ Wg1t)
{
    size_t tid = (size_t)blockIdx.x * blockDim.x + threadIdx.x;
    size_t gsz = (size_t)gridDim.x * blockDim.x;
    for (size_t i = tid; i < (size_t)Bsz * Dsz; i += gsz) {
        efb[i]  = __float2bfloat16(ef[i]);
        ctxb[i] = __float2bfloat16(ctx[i]);
    }
    for (size_t i = tid; i < 2048ull * 512; i += gsz) {     // Wt0[n][k] = W_hh0[k][n]
        size_t n = i >> 9, k = i & 511;
        Wt0[i] = __float2bfloat16(Whh0[k * 2048 + n]);
    }
    for (size_t i = tid; i < 2048ull * 1024; i += gsz) {    // Wt1[n][k] = [W_ih1; W_hh1][k][n]
        size_t n = i >> 10, k = i & 1023;
        Wt1[i] = __float2bfloat16(k < 512 ? Wih1[k * 2048 + n] : Whh1[(k - 512) * 2048 + n]);
    }
    for (size_t i = tid; i < 32ull * 512; i += gsz) {       // Wo1t/Wg1t[c][k]
        size_t c = i >> 9, k = i & 511;
        Wo1t[i] = __float2bfloat16(Wo1[k * 32 + c]);
        Wg1t[i] = __float2bfloat16(Wg1[k * 32 + c]);
    }
    for (size_t i = tid; i < 4096ull * 256; i += gsz) {     // Wit[n][k]: [Wh_init;Wc_init;W_ih0[1:]]^T
        size_t n = i >> 8, k = i & 255;
        float v = (n < 1024) ? Whi[k * 1024 + n]
                : (n < 2048) ? Wci[k * 1024 + (n - 1024)]
                             : Wih0[(1 + k) * 2048 + (n - 2048)];
        Wit[i] = __float2bfloat16(v);
    }
}

// ---------------------------------------------------------------------------
// Init GEMM: [h_init | c_init | ctx_gates]. ctx_gates stored [b][j][4 gates].
// ---------------------------------------------------------------------------
__global__ void __launch_bounds__(256)
k_init(const bf16* __restrict__ efb, const bf16* __restrict__ ctxb,
       const bf16* __restrict__ Wit,
       const float* __restrict__ bh,  const float* __restrict__ bc,
       const float* __restrict__ bi0, const float* __restrict__ bh0,
       bf16* __restrict__ h0, bf16* __restrict__ h1,
       float* __restrict__ c0, float* __restrict__ c1,
       bf16* __restrict__ ctxg)
{
    const int t = threadIdx.x, lane = t & 63, w = t >> 6;
    const int wr = w >> 1, wc = w & 1;
    const int lq = lane >> 4, ln = lane & 15;
    const int m0 = blockIdx.x * 128, n0 = blockIdx.y * 64;
    const bf16* A = (n0 < 2048) ? efb : ctxb;

    f32x4 zero = {0.f, 0.f, 0.f, 0.f};
    f32x4 acc[4][2];
#pragma unroll
    for (int r = 0; r < 4; ++r)
#pragma unroll
        for (int c = 0; c < 2; ++c) acc[r][c] = zero;

    for (int k0 = 0; k0 < 256; k0 += 32) {
        short8 af[4];
#pragma unroll
        for (int r = 0; r < 4; ++r)
            af[r] = *(const short8*)(A + (size_t)(m0 + wr * 64 + r * 16 + ln) * 256 + k0 + lq * 8);
#pragma unroll
        for (int c = 0; c < 2; ++c) {
            short8 bv = *(const short8*)(Wit + (size_t)(n0 + wc * 32 + c * 16 + ln) * 256 + k0 + lq * 8);
#pragma unroll
            for (int r = 0; r < 4; ++r)
                acc[r][c] = __builtin_amdgcn_mfma_f32_16x16x32_bf16(af[r], bv, acc[r][c], 0, 0, 0);
        }
    }
#pragma unroll
    for (int r = 0; r < 4; ++r)
#pragma unroll
        for (int c = 0; c < 2; ++c)
#pragma unroll
            for (int e = 0; e < 4; ++e) {
                int b = m0 + wr * 64 + r * 16 + lq * 4 + e;
                int n = n0 + wc * 32 + c * 16 + ln;
                float v = acc[r][c][e];
                if (n < 1024) {
                    v += bh[n];
                    if (n < 512) h0[(size_t)b * 512 + n]       = __float2bfloat16(v);
                    else         h1[(size_t)b * 512 + n - 512] = __float2bfloat16(v);
                } else if (n < 2048) {
                    int m = n - 1024; v += bc[m];
                    if (m < 512) c0[(size_t)b * 512 + m]       = v;
                    else         c1[(size_t)b * 512 + m - 512] = v;
                } else {
                    int j = n - 2048;
                    ctxg[(size_t)b * 2048 + (j & 511) * 4 + (j >> 9)] =
                        __float2bfloat16(v + bi0[j] + bh0[j]);
                }
            }
}

// ---------------------------------------------------------------------------
// intent head for 128 rows at m0 (4 waves; wave w: rows w*32..+32).
// ---------------------------------------------------------------------------
__device__ __forceinline__ void intent_head(
    const bf16* __restrict__ h, const bf16* __restrict__ W1t,
    const float* __restrict__ b1, const float* __restrict__ W2, float b2s,
    int m0, float* sitp, float* outp, int ostride)
{
    const int t = threadIdx.x, lane = t & 63, w = t >> 6;
    const int lq = lane >> 4, ln = lane & 15;
    f32x4 zero = {0.f, 0.f, 0.f, 0.f};
    f32x4 acc[2][2];
#pragma unroll
    for (int r = 0; r < 2; ++r)
#pragma unroll
        for (int c = 0; c < 2; ++c) acc[r][c] = zero;

#pragma unroll
    for (int k0 = 0; k0 < 512; k0 += 32) {
        short8 av[2], bv[2];
#pragma unroll
        for (int r = 0; r < 2; ++r)
            av[r] = *(const short8*)(h + (size_t)(m0 + w * 32 + r * 16 + ln) * 512 + k0 + lq * 8);
#pragma unroll
        for (int c = 0; c < 2; ++c)
            bv[c] = *(const short8*)(W1t + (size_t)(c * 16 + ln) * 512 + k0 + lq * 8);
#pragma unroll
        for (int r = 0; r < 2; ++r)
#pragma unroll
            for (int c = 0; c < 2; ++c)
                acc[r][c] = __builtin_amdgcn_mfma_f32_16x16x32_bf16(av[r], bv[c], acc[r][c], 0, 0, 0);
    }
#pragma unroll
    for (int r = 0; r < 2; ++r)
#pragma unroll
        for (int e = 0; e < 4; ++e) {
            float v = 0.f;
#pragma unroll
            for (int c = 0; c < 2; ++c) {
                int col = c * 16 + ln;
                v += fmaxf(acc[r][c][e] + b1[col], 0.f) * W2[col];
            }
            v += __shfl_xor(v, 1);
            v += __shfl_xor(v, 2);
            v += __shfl_xor(v, 4);
            v += __shfl_xor(v, 8);
            int row = w * 32 + r * 16 + lq * 4 + e;          // 0..127
            if (ln == 0) {
                float p = sigf(v + b2s);
                if (sitp) sitp[row] = p;
                if (outp) outp[(size_t)(m0 + row) * ostride] = p;
            }
        }
}

// ---------------------------------------------------------------------------
// Staging: one BK=32 tile (A: 128 rows x 32k = 8 KB; B: 4g x 32n x 32k = 8 KB)
// into one 16 KB ring buffer. 4 chunks/row, swizzle slot = kc ^ ((row>>1)&3)
// pre-applied on the GLOBAL side (LDS dest stays linear). 4 loads/thread.
// ---------------------------------------------------------------------------
template <int L0>
__device__ __forceinline__ void stage(const bf16* __restrict__ hA, const bf16* __restrict__ hB,
                                      const bf16* __restrict__ Wt,
                                      int m0, int j0, int k0, char* buf, int t)
{
    constexpr int KW = L0 ? 512 : 1024;
#pragma unroll
    for (int i = 0; i < 2; ++i) {
        int f = i * 256 + t;
        int row = f >> 2, slot = f & 3;
        int kk = k0 + ((slot ^ ((row >> 1) & 3)) << 3);
        const bf16* src;
        if (L0) src = hA + (size_t)(m0 + row) * Hsz + kk;
        else    src = (kk < 512) ? hA + (size_t)(m0 + row) * Hsz + kk
                                 : hB + (size_t)(m0 + row) * Hsz + (kk - 512);
        gload16(src, buf + (size_t)f * 16);
    }
#pragma unroll
    for (int i = 0; i < 2; ++i) {
        int f = i * 256 + t;
        int brow = f >> 2, slot = f & 3;               // brow = g*32+n
        int kc = slot ^ ((brow >> 1) & 3);
        gload16(Wt + (size_t)((brow >> 5) * 512 + j0 + (brow & 31)) * KW + k0 + kc * 8,
                buf + 8192 + (size_t)f * 16);
    }
}

// one BK=32 tile of MFMA work: 4 gates x 4 row-frags = 16 MFMA
__device__ __forceinline__ void mfma_tile(const char* buf,
                                          int wr, int wc, int lq, int ln,
                                          f32x4 (&acc)[4][4])
{
    const bf16* Ab = (const bf16*)buf;
    const bf16* Bb = (const bf16*)(buf + 8192);
    short8 af[4], bfr[4];
#pragma unroll
    for (int r = 0; r < 4; ++r) {
        int row = wr * 64 + r * 16 + ln;
        int slot = lq ^ ((row >> 1) & 3);
        af[r] = *(const short8*)(Ab + ((size_t)row * 4 + slot) * 8);
    }
#pragma unroll
    for (int g = 0; g < 4; ++g) {
        int brow = g * 32 + wc * 16 + ln;
        int slot = lq ^ ((brow >> 1) & 3);
        bfr[g] = *(const short8*)(Bb + ((size_t)brow * 4 + slot) * 8);
    }
#pragma unroll
    for (int g = 0; g < 4; ++g)
#pragma unroll
        for (int r = 0; r < 4; ++r)
            acc[g][r] = __builtin_amdgcn_mfma_f32_16x16x32_bf16(af[r], bfr[g], acc[g][r], 0, 0, 0);
}

#define WAIT_VM(N) asm volatile("s_waitcnt vmcnt(" #N ")" ::: "memory")

// ---------------------------------------------------------------------------
// Fused gates GEMM + LSTM cell (+ intent head for L0). 128 rows x 128 gates
// per WG; depth-3 pipelined ring-4 LDS (BK=32), counted vmcnt, raw barriers.
// XCD mapping is MBLK-MAJOR: xcd = bid&7 owns mblks {4*xcd..4*xcd+3} x all
// 16 jblks -> A-tiles, c/h state and ctxg stay resident in that XCD's L2
// across jblks AND across all 45 steps; weights stream from L3 (cheap).
// ---------------------------------------------------------------------------
template <int L0>
__global__ void __launch_bounds__(256, 2)
k_gates(const bf16* __restrict__ hA, const bf16* __restrict__ hB,
        const bf16* __restrict__ Wt,
        const bf16* __restrict__ ctxg, const float* __restrict__ ii,
        const bf16* __restrict__ h1prev,
        const float* __restrict__ w0row,
        const float* __restrict__ b1, const float* __restrict__ b2,
        const bf16* __restrict__ Wo1t, const float* __restrict__ bo1,
        const float* __restrict__ Wo2, const float* __restrict__ bo2,
        float* __restrict__ cbuf, bf16* __restrict__ hout,
        float* __restrict__ outp, int step)
{
    constexpr int KW = L0 ? 512 : 1024;
    constexpr int NT = KW / 32;
    __shared__ __align__(16) char lds[65536];          // 4 ring buffers x 16 KB
    __shared__ float sitp[128];

    const int t = threadIdx.x, lane = t & 63, w = t >> 6;
    const int wr = w >> 1, wc = w & 1, lq = lane >> 4, ln = lane & 15;
    const int bid = blockIdx.x;
    const int xcd = bid & 7, idx = bid >> 3;
    const int mblk = xcd * 4 + (idx & 3), jblk = idx >> 2;   // mblk-major per XCD
    const int j0 = jblk * 32, m0 = mblk * 128;

    // prologue: 3 stage tiles in flight (12 loads/thread)
    stage<L0>(hA, hB, Wt, m0, j0, 0,  lds,         t);
    stage<L0>(hA, hB, Wt, m0, j0, 32, lds + 16384, t);
    stage<L0>(hA, hB, Wt, m0, j0, 64, lds + 32768, t);

    float sreg[16];
    if (L0) {
        // intent head overlaps the in-flight stages
        if (step == 0) {
            if (t < 128) sitp[t] = ii[m0 + t];
        } else {
            intent_head(h1prev, Wo1t, bo1, Wo2, bo2[0], m0, sitp,
                        (jblk == 0) ? outp + (step - 1) : nullptr, Tsz);
        }
        asm volatile("s_waitcnt lgkmcnt(0)" ::: "memory");
        __builtin_amdgcn_s_barrier();                  // sitp visible to all waves
#pragma unroll
        for (int r = 0; r < 4; ++r)
#pragma unroll
            for (int e = 0; e < 4; ++e)
                sreg[r * 4 + e] = sitp[wr * 64 + r * 16 + lq * 4 + e];
    }

    f32x4 zero = {0.f, 0.f, 0.f, 0.f};
    f32x4 acc[4][4];
#pragma unroll
    for (int g = 0; g < 4; ++g)
#pragma unroll
        for (int r = 0; r < 4; ++r) acc[g][r] = zero;

    // main pipelined loop: wait own stage-kt loads (8 younger stay in flight),
    // barrier (=> whole buffer landed), compute, issue stage kt+3.
#pragma unroll 4
    for (int kt = 0; kt < NT - 3; ++kt) {
        WAIT_VM(8);
        __builtin_amdgcn_s_barrier();
        mfma_tile(lds + (size_t)(kt & 3) * 16384, wr, wc, lq, ln, acc);
        stage<L0>(hA, hB, Wt, m0, j0, (kt + 3) * 32, lds + (size_t)((kt + 3) & 3) * 16384, t);
    }
    WAIT_VM(8);
    __builtin_amdgcn_s_barrier();
    mfma_tile(lds + (size_t)((NT - 3) & 3) * 16384, wr, wc, lq, ln, acc);
    WAIT_VM(4);
    __builtin_amdgcn_s_barrier();
    mfma_tile(lds + (size_t)((NT - 2) & 3) * 16384, wr, wc, lq, ln, acc);
    WAIT_VM(0);
    __builtin_amdgcn_s_barrier();
    mfma_tile(lds + (size_t)((NT - 1) & 3) * 16384, wr, wc, lq, ln, acc);

    // ---- fused LSTM cell epilogue. C/D frag: col=lane&15, row=(lane>>4)*4+reg
    const int jl = j0 + wc * 16 + ln;
    float addc[4];
#pragma unroll
    for (int g = 0; g < 4; ++g)
        addc[g] = L0 ? w0row[g * 512 + jl] : (b1[g * 512 + jl] + b2[g * 512 + jl]);

#pragma unroll
    for (int r = 0; r < 4; ++r)
#pragma unroll
        for (int e = 0; e < 4; ++e) {
            int b = m0 + wr * 64 + r * 16 + lq * 4 + e;
            float pre[4];
#pragma unroll
            for (int g = 0; g < 4; ++g) pre[g] = acc[g][r][e];
            if (L0) {
                float it = sreg[r * 4 + e];
                us4 cg = *(const us4*)((const unsigned short*)ctxg + (size_t)b * 2048 + jl * 4);
#pragma unroll
                for (int g = 0; g < 4; ++g) pre[g] += b2f(cg[g]) + it * addc[g];
            } else {
#pragma unroll
                for (int g = 0; g < 4; ++g) pre[g] += addc[g];
            }
            float ig = sigf(pre[0]), fg = sigf(pre[1]);
            float gg = tanhft(pre[2]), og = sigf(pre[3]);
            size_t idxb = (size_t)b * Hsz + jl;
            float cn = fg * cbuf[idxb] + ig * gg;
            cbuf[idxb] = cn;
            hout[idxb] = __float2bfloat16(og * tanhft(cn));
        }
}

// ---------------------------------------------------------------------------
// standalone head (final step intent + global head), 128 rows/block
// ---------------------------------------------------------------------------
__global__ void __launch_bounds__(256)
k_intent(const bf16* __restrict__ h, const bf16* __restrict__ W1t,
         const float* __restrict__ bias1, const float* __restrict__ W2,
         const float* __restrict__ bias2,
         float* __restrict__ outp, int ostride)
{
    intent_head(h, W1t, bias1, W2, bias2[0], blockIdx.x * 128, nullptr, outp, ostride);
}

// ---------------------------------------------------------------------------
extern "C" void kernel_launch(void* const* d_in, const int* in_sizes, int n_in,
                              void* d_out, int out_size, void* d_ws, size_t ws_size,
                              hipStream_t stream)
{
    const float* ef   = (const float*)d_in[0];
    const float* ctx  = (const float*)d_in[1];
    const float* ii   = (const float*)d_in[2];
    const float* Whi  = (const float*)d_in[3];
    const float* bh   = (const float*)d_in[4];
    const float* Wci  = (const float*)d_in[5];
    const float* bc   = (const float*)d_in[6];
    const float* Wih0 = (const float*)d_in[7];
    const float* Whh0 = (const float*)d_in[8];
    const float* bi0  = (const float*)d_in[9];
    const float* bh0  = (const float*)d_in[10];
    const float* Wih1 = (const float*)d_in[11];
    const float* Whh1 = (const float*)d_in[12];
    const float* bi1  = (const float*)d_in[13];
    const float* bh1  = (const float*)d_in[14];
    const float* Wo1  = (const float*)d_in[15];
    const float* bo1  = (const float*)d_in[16];
    const float* Wo2  = (const float*)d_in[17];
    const float* bo2  = (const float*)d_in[18];
    const float* Wg1  = (const float*)d_in[19];
    const float* bg1  = (const float*)d_in[20];
    const float* Wg2  = (const float*)d_in[21];
    const float* bg2  = (const float*)d_in[22];
    float* out = (float*)d_out;

    char* ws = (char*)d_ws;
    size_t off = 0;
    auto take = [&](size_t bytes) -> char* {
        char* pp = ws + off;
        off += (bytes + 255) & ~(size_t)255;
        return pp;
    };
    bf16* Wt0    = (bf16*)take(2048ull * 512 * 2);
    bf16* Wt1    = (bf16*)take(2048ull * 1024 * 2);
    bf16* Wo1t   = (bf16*)take(32ull * 512 * 2);
    bf16* Wg1t   = (bf16*)take(32ull * 512 * 2);
    bf16* Wit    = (bf16*)take(4096ull * 256 * 2);
    bf16* efb    = (bf16*)take((size_t)Bsz * Dsz * 2);
    bf16* ctxb   = (bf16*)take((size_t)Bsz * Dsz * 2);
    bf16* h0x    = (bf16*)take((size_t)Bsz * Hsz * 2);
    bf16* h0y    = (bf16*)take((size_t)Bsz * Hsz * 2);
    bf16* h1x    = (bf16*)take((size_t)Bsz * Hsz * 2);
    bf16* h1y    = (bf16*)take((size_t)Bsz * Hsz * 2);
    float* c0    = (float*)take((size_t)Bsz * Hsz * 4);
    float* c1    = (float*)take((size_t)Bsz * Hsz * 4);
    bf16* ctxg   = (bf16*)take((size_t)Bsz * 2048 * 2);
    (void)ws_size; (void)in_sizes; (void)n_in; (void)out_size;

    k_conv<<<2048, 256, 0, stream>>>(ef, ctx, Whi, Wci, Wih0, Whh0, Wih1, Whh1, Wo1, Wg1,
                                     efb, ctxb, Wit, Wt0, Wt1, Wo1t, Wg1t);
    k_init<<<dim3(32, 64), 256, 0, stream>>>(efb, ctxb, Wit, bh, bc, bi0, bh0,
                                             h0x, h1x, c0, c1, ctxg);

    for (int s = 0; s < Tsz; ++s) {
        int p = s & 1;
        const bf16* h0in  = p ? h0y : h0x;
        bf16*       h0out = p ? h0x : h0y;
        const bf16* h1in  = p ? h1y : h1x;
        bf16*       h1out = p ? h1x : h1y;
        k_gates<1><<<512, 256, 0, stream>>>(
            h0in, nullptr, Wt0, ctxg, ii, h1in, Wih0, nullptr, nullptr,
            Wo1t, bo1, Wo2, bo2, c0, h0out, out, s);
        k_gates<0><<<512, 256, 0, stream>>>(
            h0out, h1in, Wt1, nullptr, nullptr, nullptr, nullptr, bi1, bh1,
            nullptr, nullptr, nullptr, nullptr, c1, h1out, nullptr, s);
    }
    // s=44 wrote h1y; remaining outputs: step col 44 + global head
    k_intent<<<32, 256, 0, stream>>>(h1y, Wo1t, bo1, Wo2, bo2, out + 44, Tsz);
    k_intent<<<32, 256, 0, stream>>>(h1y, Wg1t, bg1, Wg2, bg2, out + (size_t)Bsz * Tsz, 1);
}